// Round 2
// baseline (2500.217 us; speedup 1.0000x reference)
//
#include <hip/hip_runtime.h>
#include <math.h>

// ---------------------------------------------------------------------------
// Fused GEMM (+bias [+LayerNorm] +ReLU): out = act(LN(A[M,K] @ W[K,N] + b))
// Block: 256 threads, tile = 64 rows x N cols (full N so LN fits in-block).
// ty = tid>>5 (0..7) owns rows ty*8..ty*8+7 ; tx = tid&31 owns cols tx*CT..
// LN row reduction = intra-thread + __shfl_xor over the 32 lanes of a row.
// ---------------------------------------------------------------------------

constexpr int MT = 64;
constexpr int KT = 32;

template<int K, int N, int CT>
__device__ __forceinline__ void gemm_core(
    const float* __restrict__ A, const float* __restrict__ W,
    int m0, int tid, int ty, int tx,
    float (&acc)[8][CT],
    float (*As)[MT + 4], float (*Bs)[N]) {
  constexpr int N4 = N / 4;
  const int ar  = tid >> 3;   // 0..31
  const int ak4 = tid & 7;    // 0..7

  for (int kt = 0; kt < K; kt += KT) {
    __syncthreads();
    #pragma unroll
    for (int h = 0; h < 2; ++h) {
      const int row = ar + h * 32;
      const float4 av = *(const float4*)(A + (size_t)(m0 + row) * K + kt + ak4 * 4);
      As[ak4 * 4 + 0][row] = av.x;
      As[ak4 * 4 + 1][row] = av.y;
      As[ak4 * 4 + 2][row] = av.z;
      As[ak4 * 4 + 3][row] = av.w;
    }
    #pragma unroll
    for (int f = 0; f < (KT * N4) / 256; ++f) {
      const int idx = tid + f * 256;
      const int br = idx / N4;
      const int bc = idx % N4;
      *(float4*)(&Bs[br][bc * 4]) = *(const float4*)(W + (size_t)(kt + br) * N + bc * 4);
    }
    __syncthreads();

    #pragma unroll 4
    for (int kk = 0; kk < KT; ++kk) {
      float a[8];
      *(float4*)(&a[0]) = *(const float4*)(&As[kk][ty * 8]);
      *(float4*)(&a[4]) = *(const float4*)(&As[kk][ty * 8 + 4]);
      float b[CT];
      if constexpr (CT % 4 == 0) {
        #pragma unroll
        for (int j4 = 0; j4 < CT / 4; ++j4)
          *(float4*)(&b[j4 * 4]) = *(const float4*)(&Bs[kk][tx * CT + j4 * 4]);
      } else {
        *(float2*)(&b[0]) = *(const float2*)(&Bs[kk][tx * CT]);
      }
      #pragma unroll
      for (int i = 0; i < 8; ++i)
        #pragma unroll
        for (int j = 0; j < CT; ++j)
          acc[i][j] = fmaf(a[i], b[j], acc[i][j]);
    }
  }
}

template<int CT, int N>
__device__ __forceinline__ void ln_relu_row(float (&row)[CT],
                                            const float* ga, const float* be) {
  float s = 0.f;
  #pragma unroll
  for (int j = 0; j < CT; ++j) s += row[j];
  #pragma unroll
  for (int off = 16; off > 0; off >>= 1) s += __shfl_xor(s, off, 32);
  const float m = s * (1.f / N);
  float q = 0.f;
  #pragma unroll
  for (int j = 0; j < CT; ++j) { const float d = row[j] - m; q += d * d; }
  #pragma unroll
  for (int off = 16; off > 0; off >>= 1) q += __shfl_xor(q, off, 32);
  const float inv = rsqrtf(q * (1.f / N) + 1e-5f);
  #pragma unroll
  for (int j = 0; j < CT; ++j)
    row[j] = fmaxf((row[j] - m) * inv * ga[j] + be[j], 0.f);
}

// ---- generic GEMM (+bias [+LN] +ReLU) -> writes result --------------------
template<int K, int N, bool DO_LN>
__global__ __launch_bounds__(256, 2)
void gemm_ln(const float* __restrict__ A, const float* __restrict__ W,
             const float* __restrict__ bias, const float* __restrict__ gamma,
             const float* __restrict__ beta, float* __restrict__ out) {
  constexpr int CT = N / 32;
  __shared__ __align__(16) float As[KT][MT + 4];
  __shared__ __align__(16) float Bs[KT][N];
  const int tid = threadIdx.x, ty = tid >> 5, tx = tid & 31;
  const int m0 = blockIdx.x * MT;

  float acc[8][CT];
  #pragma unroll
  for (int i = 0; i < 8; ++i)
    #pragma unroll
    for (int j = 0; j < CT; ++j) acc[i][j] = 0.f;

  gemm_core<K, N, CT>(A, W, m0, tid, ty, tx, acc, As, Bs);

  float bi[CT], ga[CT], be[CT];
  #pragma unroll
  for (int j = 0; j < CT; ++j) {
    bi[j] = bias[tx * CT + j];
    if constexpr (DO_LN) { ga[j] = gamma[tx * CT + j]; be[j] = beta[tx * CT + j]; }
  }

  #pragma unroll
  for (int i = 0; i < 8; ++i) {
    #pragma unroll
    for (int j = 0; j < CT; ++j) acc[i][j] += bi[j];
    if constexpr (DO_LN) {
      ln_relu_row<CT, N>(acc[i], ga, be);
    } else {
      #pragma unroll
      for (int j = 0; j < CT; ++j) acc[i][j] = fmaxf(acc[i][j], 0.f);
    }
  }

  #pragma unroll
  for (int i = 0; i < 8; ++i) {
    const size_t ro = (size_t)(m0 + ty * 8 + i) * N + tx * CT;
    if constexpr (CT % 4 == 0) {
      #pragma unroll
      for (int j4 = 0; j4 < CT / 4; ++j4)
        *(float4*)(out + ro + j4 * 4) = *(const float4*)(&acc[i][j4 * 4]);
    } else {
      *(float2*)(out + ro) = *(const float2*)(&acc[i][0]);
    }
  }
}

// ---- L3 GEMM + LN + ReLU + fused gate-combine accumulation into d_out -----
// Expert e's output tile (64 rows x 128 cols) is weighted by the gates and
// accumulated into out slices: shared (slice 3) always; tasks 0..2 if e<4;
// task (e-4)/2 if e>=4.  e==0 initializes (d_out is poisoned pre-launch).
__global__ __launch_bounds__(256, 2)
void gemm_l3_combine(const float* __restrict__ A, const float* __restrict__ W,
                     const float* __restrict__ bias,
                     const float* __restrict__ gamma,
                     const float* __restrict__ beta,
                     const float* __restrict__ gw,   // [3][B][6]
                     const float* __restrict__ sgw,  // [B][10]
                     float* __restrict__ out,        // [4][B][128]
                     int e, int B) {
  constexpr int K = 256, N = 128, CT = 4;
  __shared__ __align__(16) float As[KT][MT + 4];
  __shared__ __align__(16) float Bs[KT][N];
  const int tid = threadIdx.x, ty = tid >> 5, tx = tid & 31;
  const int m0 = blockIdx.x * MT;

  float acc[8][CT];
  #pragma unroll
  for (int i = 0; i < 8; ++i)
    #pragma unroll
    for (int j = 0; j < CT; ++j) acc[i][j] = 0.f;

  gemm_core<K, N, CT>(A, W, m0, tid, ty, tx, acc, As, Bs);

  float bi[CT], ga[CT], be[CT];
  #pragma unroll
  for (int j = 0; j < CT; ++j) {
    bi[j] = bias[tx * CT + j];
    ga[j] = gamma[tx * CT + j];
    be[j] = beta[tx * CT + j];
  }

  const size_t BO = (size_t)B * N;

  #pragma unroll
  for (int i = 0; i < 8; ++i) {
    #pragma unroll
    for (int j = 0; j < CT; ++j) acc[i][j] += bi[j];
    ln_relu_row<CT, N>(acc[i], ga, be);

    const int b = m0 + ty * 8 + i;
    const size_t co = (size_t)b * N + tx * CT;
    const float4 v = {acc[i][0], acc[i][1], acc[i][2], acc[i][3]};

    // shared-out slice (index 3)
    {
      const float g = sgw[(size_t)b * 10 + e];
      float4* p = (float4*)(out + 3 * BO + co);
      if (e == 0) {
        float4 r = {g * v.x, g * v.y, g * v.z, g * v.w};
        *p = r;
      } else {
        float4 r = *p;
        r.x = fmaf(g, v.x, r.x); r.y = fmaf(g, v.y, r.y);
        r.z = fmaf(g, v.z, r.z); r.w = fmaf(g, v.w, r.w);
        *p = r;
      }
    }
    if (e < 4) {   // shared expert: feeds gate slot e of every task
      #pragma unroll
      for (int t = 0; t < 3; ++t) {
        const float g = gw[((size_t)t * B + b) * 6 + e];
        float4* p = (float4*)(out + (size_t)t * BO + co);
        if (e == 0) {
          float4 r = {g * v.x, g * v.y, g * v.z, g * v.w};
          *p = r;
        } else {
          float4 r = *p;
          r.x = fmaf(g, v.x, r.x); r.y = fmaf(g, v.y, r.y);
          r.z = fmaf(g, v.z, r.z); r.w = fmaf(g, v.w, r.w);
          *p = r;
        }
      }
    } else {       // task expert: feeds gate slot 4/5 of exactly one task
      const int t = (e - 4) >> 1;
      const int slot = 4 + ((e - 4) & 1);
      const float g = gw[((size_t)t * B + b) * 6 + slot];
      float4* p = (float4*)(out + (size_t)t * BO + co);
      float4 r = *p;
      r.x = fmaf(g, v.x, r.x); r.y = fmaf(g, v.y, r.y);
      r.z = fmaf(g, v.z, r.z); r.w = fmaf(g, v.w, r.w);
      *p = r;
    }
  }
}

// ---------------------------------------------------------------------------
// Gating layer 2: softmax(gh @ w2 + b2) over NOUT outputs, one slice.
// ---------------------------------------------------------------------------
template<int NOUT>
__global__ __launch_bounds__(256)
void gate2(const float* __restrict__ gh, const float* __restrict__ w2,
           const float* __restrict__ b2, float* __restrict__ outw, int B) {
  const int b0 = blockIdx.x * 64;
  __shared__ float ghs[64][65];
  __shared__ float wls[64 * NOUT];
  __shared__ float bls[NOUT];
  const int tid = threadIdx.x;

  const float* src = gh + (size_t)b0 * 64;
  for (int f = tid; f < 64 * 16; f += 256) {
    const int r = f >> 4, c4 = f & 15;
    const float4 v = *(const float4*)(src + r * 64 + c4 * 4);
    ghs[r][c4 * 4 + 0] = v.x;
    ghs[r][c4 * 4 + 1] = v.y;
    ghs[r][c4 * 4 + 2] = v.z;
    ghs[r][c4 * 4 + 3] = v.w;
  }
  for (int f = tid; f < 64 * NOUT; f += 256) wls[f] = w2[f];
  if (tid < NOUT) bls[tid] = b2[tid];
  __syncthreads();

  if (tid < 64) {
    const int b = b0 + tid;
    float a[NOUT];
    #pragma unroll
    for (int n = 0; n < NOUT; ++n) a[n] = bls[n];
    for (int k = 0; k < 64; ++k) {
      const float g = ghs[tid][k];
      #pragma unroll
      for (int n = 0; n < NOUT; ++n) a[n] = fmaf(g, wls[k * NOUT + n], a[n]);
    }
    float mx = a[0];
    #pragma unroll
    for (int n = 1; n < NOUT; ++n) mx = fmaxf(mx, a[n]);
    float sum = 0.f;
    #pragma unroll
    for (int n = 0; n < NOUT; ++n) { a[n] = expf(a[n] - mx); sum += a[n]; }
    const float r = 1.f / sum;
    #pragma unroll
    for (int n = 0; n < NOUT; ++n) outw[(size_t)b * NOUT + n] = a[n] * r;
  }
}

// ---------------------------------------------------------------------------
extern "C" void kernel_launch(void* const* d_in, const int* in_sizes, int n_in,
                              void* d_out, int out_size, void* d_ws, size_t ws_size,
                              hipStream_t stream) {
  const float* x     = (const float*)d_in[0];
  const float* ew1   = (const float*)d_in[1];
  const float* eb1   = (const float*)d_in[2];
  const float* eg1   = (const float*)d_in[3];
  const float* ebt1  = (const float*)d_in[4];
  const float* ew2   = (const float*)d_in[5];
  const float* eb2   = (const float*)d_in[6];
  const float* eg2   = (const float*)d_in[7];
  const float* ebt2  = (const float*)d_in[8];
  const float* ew3   = (const float*)d_in[9];
  const float* eb3   = (const float*)d_in[10];
  const float* eg3   = (const float*)d_in[11];
  const float* ebt3  = (const float*)d_in[12];
  const float* tg_w1 = (const float*)d_in[13];
  const float* tg_b1 = (const float*)d_in[14];
  const float* tg_w2 = (const float*)d_in[15];
  const float* tg_b2 = (const float*)d_in[16];
  const float* sg_w1 = (const float*)d_in[17];
  const float* sg_b1 = (const float*)d_in[18];
  const float* sg_w2 = (const float*)d_in[19];
  const float* sg_b2 = (const float*)d_in[20];
  float* out = (float*)d_out;

  const int B = 32768, D = 512, H = 256, G = 64, E = 10;

  // Workspace (floats), total ~79.2 MB
  float* ws   = (float*)d_ws;
  float* h1   = ws;  ws += (size_t)B * H;       // 33.55 MB
  float* h2   = ws;  ws += (size_t)B * H;       // 33.55 MB
  float* gh   = ws;  ws += (size_t)B * G;       //  8.39 MB (reused per slice)
  float* gwb  = ws;  ws += (size_t)3 * B * 6;   //  2.36 MB
  float* sgwb = ws;                             //  1.31 MB

  dim3 blk(256);

  // Gating: for each of 3 task gates + 1 shared gate, hidden then softmax.
  for (int t = 0; t < 4; ++t) {
    const float* W1 = (t < 3) ? tg_w1 + (size_t)t * D * G : sg_w1;
    const float* b1 = (t < 3) ? tg_b1 + (size_t)t * G : sg_b1;
    gemm_ln<512, 64, false><<<B / 64, blk, 0, stream>>>(x, W1, b1, nullptr,
                                                        nullptr, gh);
    if (t < 3) {
      gate2<6><<<B / 64, blk, 0, stream>>>(gh, tg_w2 + (size_t)t * G * 6,
                                           tg_b2 + (size_t)t * 6,
                                           gwb + (size_t)t * B * 6, B);
    } else {
      gate2<10><<<B / 64, blk, 0, stream>>>(gh, sg_w2, sg_b2, sgwb, B);
    }
  }

  // Expert towers; L3 fuses gate-combine accumulation into d_out.
  for (int e = 0; e < E; ++e) {
    gemm_ln<512, 256, true><<<B / 64, blk, 0, stream>>>(
        x, ew1 + (size_t)e * D * H, eb1 + e * H, eg1 + e * H, ebt1 + e * H, h1);
    gemm_ln<256, 256, true><<<B / 64, blk, 0, stream>>>(
        h1, ew2 + (size_t)e * H * H, eb2 + e * H, eg2 + e * H, ebt2 + e * H, h2);
    gemm_l3_combine<<<B / 64, blk, 0, stream>>>(
        h2, ew3 + (size_t)e * H * 128, eb3 + e * 128, eg3 + e * 128,
        ebt3 + e * 128, gwb, sgwb, out, e, B);
  }
}

// Round 3
// 1535.444 us; speedup vs baseline: 1.6283x; 1.6283x over previous
//
#include <hip/hip_runtime.h>
#include <math.h>

typedef __attribute__((ext_vector_type(8))) short short8;   // 8 bf16 = 4 VGPRs
typedef __attribute__((ext_vector_type(4))) float float4v;  // MFMA C/D

// ---------------- bf16 helpers (raw bit manipulation, RN) -------------------
static __device__ __forceinline__ unsigned short f2bf(float f) {
  unsigned u = __float_as_uint(f);
  u += 0x7fffu + ((u >> 16) & 1u);
  return (unsigned short)(u >> 16);
}
static __device__ __forceinline__ float bf2f(unsigned short h) {
  return __uint_as_float(((unsigned)h) << 16);
}

// ---------------------------------------------------------------------------
// split_act: fp32 -> bf16 hi + bf16 lo (residual), elementwise.
// ---------------------------------------------------------------------------
__global__ __launch_bounds__(256)
void split_act(const float* __restrict__ s, unsigned short* __restrict__ h,
               unsigned short* __restrict__ l) {
  const int i = (blockIdx.x * 256 + threadIdx.x) * 4;
  const float4 v = *(const float4*)(s + i);
  ushort4 hv, lv;
  hv.x = f2bf(v.x); lv.x = f2bf(v.x - bf2f(hv.x));
  hv.y = f2bf(v.y); lv.y = f2bf(v.y - bf2f(hv.y));
  hv.z = f2bf(v.z); lv.z = f2bf(v.z - bf2f(hv.z));
  hv.w = f2bf(v.w); lv.w = f2bf(v.w - bf2f(hv.w));
  *(ushort4*)(h + i) = hv;
  *(ushort4*)(l + i) = lv;
}

// ---------------------------------------------------------------------------
// split_wT: weights [nmat][K][N] fp32 -> transposed bf16 hi/lo [nmat][N][K].
// 32x32 LDS tile transpose; grid (K/32, N/32, nmat), 256 threads.
// ---------------------------------------------------------------------------
__global__ __launch_bounds__(256)
void split_wT(const float* __restrict__ src, unsigned short* __restrict__ dh,
              unsigned short* __restrict__ dl, int K, int N) {
  __shared__ float t[32][33];
  const size_t mo = (size_t)blockIdx.z * K * N;
  src += mo; dh += mo; dl += mo;
  const int k0 = blockIdx.x * 32, n0 = blockIdx.y * 32;
  const int tid = threadIdx.x;
  const int r = tid >> 3, c4 = (tid & 7) * 4;

  const float4 v = *(const float4*)(src + (size_t)(k0 + r) * N + n0 + c4);
  t[r][c4 + 0] = v.x; t[r][c4 + 1] = v.y; t[r][c4 + 2] = v.z; t[r][c4 + 3] = v.w;
  __syncthreads();

  ushort4 hv, lv;
  float f;
  f = t[c4 + 0][r]; hv.x = f2bf(f); lv.x = f2bf(f - bf2f(hv.x));
  f = t[c4 + 1][r]; hv.y = f2bf(f); lv.y = f2bf(f - bf2f(hv.y));
  f = t[c4 + 2][r]; hv.z = f2bf(f); lv.z = f2bf(f - bf2f(hv.z));
  f = t[c4 + 3][r]; hv.w = f2bf(f); lv.w = f2bf(f - bf2f(hv.w));
  const size_t o = (size_t)(n0 + r) * K + k0 + c4;
  *(ushort4*)(dh + o) = hv;
  *(ushort4*)(dl + o) = lv;
}

// ---------------------------------------------------------------------------
// MFMA GEMM: C[M,N] = A[M,K] @ B^T[N,K] via 16x16x32 bf16, split precision:
//   acc += Ah*Bh + Ah*Bl + Al*Bh   (fp32 accumulate)
// Block = 128 threads = 2 waves; tile = 64 rows x full N (LN over N in-block).
// Wave w: rows w*32..w*32+31 (2 m-subtiles of 16). LDS rows padded to 40 bf16
// (80B stride) -> even bank-group spread for quarter-wave b128 access.
// MODE 0: +bias, LN, ReLU -> split bf16 out (outh/outl, stride N)
// MODE 1: +bias, ReLU -> fp32 out (stride N)
// MODE 2: +bias, LN, ReLU -> gate-combine RMW into outf[4][B][128]
// ---------------------------------------------------------------------------
template<int K, int N, int MODE>
__global__ __launch_bounds__(128, 2)
void mfma_gemm(const unsigned short* __restrict__ Ah,
               const unsigned short* __restrict__ Al,
               const unsigned short* __restrict__ Bh,
               const unsigned short* __restrict__ Bl,
               const float* __restrict__ bias, const float* __restrict__ gamma,
               const float* __restrict__ beta,
               unsigned short* __restrict__ outh,
               unsigned short* __restrict__ outl,
               float* __restrict__ outf,
               const float* __restrict__ gw, const float* __restrict__ sgw,
               int e, int Btot) {
  constexpr int NT = N / 16;          // n-tiles
  constexpr int BCH = (N * 4) / 128;  // B 16B-chunks per thread
  __shared__ __align__(16) unsigned short lAh[64 * 40], lAl[64 * 40];
  __shared__ __align__(16) unsigned short lBh[N * 40], lBl[N * 40];

  const int tid = threadIdx.x;
  const int m0 = blockIdx.x * 64;
  const int lane = tid & 63;
  const int w = tid >> 6;
  const int m = lane & 15, q = lane >> 4;

  float4v acc[2][NT];
  #pragma unroll
  for (int s = 0; s < 2; ++s)
    #pragma unroll
    for (int t = 0; t < NT; ++t) acc[s][t] = (float4v){0.f, 0.f, 0.f, 0.f};

  for (int kt = 0; kt < K; kt += 32) {
    // ---- global loads into regs ----
    short8 ra[2], rla[2];
    #pragma unroll
    for (int i = 0; i < 2; ++i) {
      const int c = tid + i * 128, row = c >> 2, p = c & 3;
      const size_t go = (size_t)(m0 + row) * K + kt + p * 8;
      ra[i]  = *(const short8*)(Ah + go);
      rla[i] = *(const short8*)(Al + go);
    }
    short8 rb[BCH], rlb[BCH];
    #pragma unroll
    for (int i = 0; i < BCH; ++i) {
      const int c = tid + i * 128, n = c >> 2, p = c & 3;
      const size_t go = (size_t)n * K + kt + p * 8;
      rb[i]  = *(const short8*)(Bh + go);
      rlb[i] = *(const short8*)(Bl + go);
    }
    __syncthreads();
    // ---- LDS writes ----
    #pragma unroll
    for (int i = 0; i < 2; ++i) {
      const int c = tid + i * 128, row = c >> 2, p = c & 3;
      *(short8*)(&lAh[row * 40 + p * 8]) = ra[i];
      *(short8*)(&lAl[row * 40 + p * 8]) = rla[i];
    }
    #pragma unroll
    for (int i = 0; i < BCH; ++i) {
      const int c = tid + i * 128, n = c >> 2, p = c & 3;
      *(short8*)(&lBh[n * 40 + p * 8]) = rb[i];
      *(short8*)(&lBl[n * 40 + p * 8]) = rlb[i];
    }
    __syncthreads();
    // ---- fragments + MFMA ----
    short8 ah[2], al[2];
    #pragma unroll
    for (int s = 0; s < 2; ++s) {
      const int off = (w * 32 + s * 16 + m) * 40 + q * 8;
      ah[s] = *(const short8*)(&lAh[off]);
      al[s] = *(const short8*)(&lAl[off]);
    }
    #pragma unroll
    for (int t = 0; t < NT; ++t) {
      const int off = (t * 16 + m) * 40 + q * 8;
      const short8 bh = *(const short8*)(&lBh[off]);
      const short8 bl = *(const short8*)(&lBl[off]);
      #pragma unroll
      for (int s = 0; s < 2; ++s) {
        acc[s][t] = __builtin_amdgcn_mfma_f32_16x16x32_bf16(ah[s], bh, acc[s][t], 0, 0, 0);
        acc[s][t] = __builtin_amdgcn_mfma_f32_16x16x32_bf16(ah[s], bl, acc[s][t], 0, 0, 0);
        acc[s][t] = __builtin_amdgcn_mfma_f32_16x16x32_bf16(al[s], bh, acc[s][t], 0, 0, 0);
      }
    }
  }

  // ---- epilogue ----
  float cb[NT], cg[NT], cbt[NT];
  #pragma unroll
  for (int t = 0; t < NT; ++t) {
    cb[t] = bias[t * 16 + m];
    if constexpr (MODE != 1) {
      cg[t]  = gamma[t * 16 + m];
      cbt[t] = beta[t * 16 + m];
    }
  }

  #pragma unroll
  for (int s = 0; s < 2; ++s) {
    #pragma unroll
    for (int r = 0; r < 4; ++r) {
      const int row = m0 + w * 32 + s * 16 + q * 4 + r;
      if constexpr (MODE == 1) {
        #pragma unroll
        for (int t = 0; t < NT; ++t) {
          const float o = fmaxf(acc[s][t][r] + cb[t], 0.f);
          outf[(size_t)row * N + t * 16 + m] = o;
        }
      } else {
        float v[NT];
        float sum = 0.f;
        #pragma unroll
        for (int t = 0; t < NT; ++t) { v[t] = acc[s][t][r] + cb[t]; sum += v[t]; }
        #pragma unroll
        for (int off = 1; off < 16; off <<= 1) sum += __shfl_xor(sum, off, 16);
        const float mean = sum * (1.f / N);
        float q2 = 0.f;
        #pragma unroll
        for (int t = 0; t < NT; ++t) { const float d = v[t] - mean; q2 += d * d; }
        #pragma unroll
        for (int off = 1; off < 16; off <<= 1) q2 += __shfl_xor(q2, off, 16);
        const float inv = rsqrtf(q2 * (1.f / N) + 1e-5f);
        float ov[NT];
        #pragma unroll
        for (int t = 0; t < NT; ++t)
          ov[t] = fmaxf((v[t] - mean) * inv * cg[t] + cbt[t], 0.f);

        if constexpr (MODE == 0) {
          #pragma unroll
          for (int t = 0; t < NT; ++t) {
            const size_t o = (size_t)row * N + t * 16 + m;
            const unsigned short hb = f2bf(ov[t]);
            outh[o] = hb;
            outl[o] = f2bf(ov[t] - bf2f(hb));
          }
        } else {  // MODE 2: gate-combine into outf[4][B][128]
          const size_t BO = (size_t)Btot * 128;
          const float gsh = sgw[(size_t)row * 10 + e];
          float* p3 = outf + 3 * BO + (size_t)row * 128;
          #pragma unroll
          for (int t = 0; t < NT; ++t) {
            const int n = t * 16 + m;
            if (e == 0) p3[n] = gsh * ov[t];
            else        p3[n] = fmaf(gsh, ov[t], p3[n]);
          }
          if (e < 4) {  // shared expert -> gate slot e of every task
            for (int tt = 0; tt < 3; ++tt) {
              const float g = gw[((size_t)tt * Btot + row) * 6 + e];
              float* p = outf + (size_t)tt * BO + (size_t)row * 128;
              #pragma unroll
              for (int t = 0; t < NT; ++t) {
                const int n = t * 16 + m;
                if (e == 0) p[n] = g * ov[t];
                else        p[n] = fmaf(g, ov[t], p[n]);
              }
            }
          } else {      // task expert -> slot 4/5 of one task
            const int tt = (e - 4) >> 1;
            const int slot = 4 + ((e - 4) & 1);
            const float g = gw[((size_t)tt * Btot + row) * 6 + slot];
            float* p = outf + (size_t)tt * BO + (size_t)row * 128;
            #pragma unroll
            for (int t = 0; t < NT; ++t) {
              const int n = t * 16 + m;
              p[n] = fmaf(g, ov[t], p[n]);
            }
          }
        }
      }
    }
  }
}

// ---------------------------------------------------------------------------
// Gating layer 2: softmax(gh @ w2 + b2) over NOUT outputs (unchanged, passed).
// ---------------------------------------------------------------------------
template<int NOUT>
__global__ __launch_bounds__(256)
void gate2(const float* __restrict__ gh, const float* __restrict__ w2,
           const float* __restrict__ b2, float* __restrict__ outw, int B) {
  const int b0 = blockIdx.x * 64;
  __shared__ float ghs[64][65];
  __shared__ float wls[64 * NOUT];
  __shared__ float bls[NOUT];
  const int tid = threadIdx.x;

  const float* src = gh + (size_t)b0 * 64;
  for (int f = tid; f < 64 * 16; f += 256) {
    const int r = f >> 4, c4 = f & 15;
    const float4 v = *(const float4*)(src + r * 64 + c4 * 4);
    ghs[r][c4 * 4 + 0] = v.x;
    ghs[r][c4 * 4 + 1] = v.y;
    ghs[r][c4 * 4 + 2] = v.z;
    ghs[r][c4 * 4 + 3] = v.w;
  }
  for (int f = tid; f < 64 * NOUT; f += 256) wls[f] = w2[f];
  if (tid < NOUT) bls[tid] = b2[tid];
  __syncthreads();

  if (tid < 64) {
    const int b = b0 + tid;
    float a[NOUT];
    #pragma unroll
    for (int n = 0; n < NOUT; ++n) a[n] = bls[n];
    for (int k = 0; k < 64; ++k) {
      const float g = ghs[tid][k];
      #pragma unroll
      for (int n = 0; n < NOUT; ++n) a[n] = fmaf(g, wls[k * NOUT + n], a[n]);
    }
    float mx = a[0];
    #pragma unroll
    for (int n = 1; n < NOUT; ++n) mx = fmaxf(mx, a[n]);
    float sum = 0.f;
    #pragma unroll
    for (int n = 0; n < NOUT; ++n) { a[n] = expf(a[n] - mx); sum += a[n]; }
    const float r = 1.f / sum;
    #pragma unroll
    for (int n = 0; n < NOUT; ++n) outw[(size_t)b * NOUT + n] = a[n] * r;
  }
}

// ---------------------------------------------------------------------------
extern "C" void kernel_launch(void* const* d_in, const int* in_sizes, int n_in,
                              void* d_out, int out_size, void* d_ws, size_t ws_size,
                              hipStream_t stream) {
  const float* x     = (const float*)d_in[0];
  const float* ew1   = (const float*)d_in[1];
  const float* eb1   = (const float*)d_in[2];
  const float* eg1   = (const float*)d_in[3];
  const float* ebt1  = (const float*)d_in[4];
  const float* ew2   = (const float*)d_in[5];
  const float* eb2   = (const float*)d_in[6];
  const float* eg2   = (const float*)d_in[7];
  const float* ebt2  = (const float*)d_in[8];
  const float* ew3   = (const float*)d_in[9];
  const float* eb3   = (const float*)d_in[10];
  const float* eg3   = (const float*)d_in[11];
  const float* ebt3  = (const float*)d_in[12];
  const float* tg_w1 = (const float*)d_in[13];
  const float* tg_b1 = (const float*)d_in[14];
  const float* tg_w2 = (const float*)d_in[15];
  const float* tg_b2 = (const float*)d_in[16];
  const float* sg_w1 = (const float*)d_in[17];
  const float* sg_b1 = (const float*)d_in[18];
  const float* sg_w2 = (const float*)d_in[19];
  const float* sg_b2 = (const float*)d_in[20];
  float* out = (float*)d_out;

  const int B = 32768, D = 512, H = 256, O = 128, G = 64, E = 10;

  // ---- workspace layout (bytes), total ~122.4 MB ----
  char* p = (char*)d_ws;
  unsigned short* xh    = (unsigned short*)p; p += (size_t)B * D * 2;      // 33.55 MB
  unsigned short* xl    = (unsigned short*)p; p += (size_t)B * D * 2;
  unsigned short* w1h   = (unsigned short*)p; p += (size_t)E * H * D * 2;  //  2.62 MB
  unsigned short* w1l   = (unsigned short*)p; p += (size_t)E * H * D * 2;
  unsigned short* w2h   = (unsigned short*)p; p += (size_t)E * H * H * 2;  //  1.31 MB
  unsigned short* w2l   = (unsigned short*)p; p += (size_t)E * H * H * 2;
  unsigned short* w3h   = (unsigned short*)p; p += (size_t)E * O * H * 2;  //  0.66 MB
  unsigned short* w3l   = (unsigned short*)p; p += (size_t)E * O * H * 2;
  unsigned short* tw1h  = (unsigned short*)p; p += (size_t)3 * G * D * 2;  //  0.20 MB
  unsigned short* tw1l  = (unsigned short*)p; p += (size_t)3 * G * D * 2;
  unsigned short* sw1h  = (unsigned short*)p; p += (size_t)G * D * 2;      //  0.07 MB
  unsigned short* sw1l  = (unsigned short*)p; p += (size_t)G * D * 2;
  unsigned short* hh    = (unsigned short*)p; p += (size_t)B * H * 2;      // 16.78 MB (in-place L1->L2->L3)
  unsigned short* hl    = (unsigned short*)p; p += (size_t)B * H * 2;
  float* gh   = (float*)p; p += (size_t)B * G * 4;                         //  8.39 MB
  float* gwb  = (float*)p; p += (size_t)3 * B * 6 * 4;                     //  2.36 MB
  float* sgwb = (float*)p;                                                 //  1.31 MB

  // ---- 1. conversions ----
  split_act<<<(B * D) / 1024, 256, 0, stream>>>(x, xh, xl);
  split_wT<<<dim3(D / 32, H / 32, E), 256, 0, stream>>>(ew1, w1h, w1l, D, H);
  split_wT<<<dim3(H / 32, H / 32, E), 256, 0, stream>>>(ew2, w2h, w2l, H, H);
  split_wT<<<dim3(H / 32, O / 32, E), 256, 0, stream>>>(ew3, w3h, w3l, H, O);
  split_wT<<<dim3(D / 32, G / 32, 3), 256, 0, stream>>>(tg_w1, tw1h, tw1l, D, G);
  split_wT<<<dim3(D / 32, G / 32, 1), 256, 0, stream>>>(sg_w1, sw1h, sw1l, D, G);

  const int grid = B / 64;

  // ---- 2. gating ----
  for (int t = 0; t < 4; ++t) {
    const unsigned short* Wh = (t < 3) ? tw1h + (size_t)t * G * D : sw1h;
    const unsigned short* Wl = (t < 3) ? tw1l + (size_t)t * G * D : sw1l;
    const float* b1 = (t < 3) ? tg_b1 + (size_t)t * G : sg_b1;
    mfma_gemm<512, 64, 1><<<grid, 128, 0, stream>>>(
        xh, xl, Wh, Wl, b1, nullptr, nullptr, nullptr, nullptr, gh,
        nullptr, nullptr, 0, B);
    if (t < 3)
      gate2<6><<<B / 64, 256, 0, stream>>>(gh, tg_w2 + (size_t)t * G * 6,
                                           tg_b2 + (size_t)t * 6,
                                           gwb + (size_t)t * B * 6, B);
    else
      gate2<10><<<B / 64, 256, 0, stream>>>(gh, sg_w2, sg_b2, sgwb, B);
  }

  // ---- 3. expert towers (L2 in-place on h; L3 fuses gate combine) ----
  for (int e = 0; e < E; ++e) {
    mfma_gemm<512, 256, 0><<<grid, 128, 0, stream>>>(
        xh, xl, w1h + (size_t)e * H * D, w1l + (size_t)e * H * D,
        eb1 + (size_t)e * H, eg1 + (size_t)e * H, ebt1 + (size_t)e * H,
        hh, hl, nullptr, nullptr, nullptr, 0, B);
    mfma_gemm<256, 256, 0><<<grid, 128, 0, stream>>>(
        hh, hl, w2h + (size_t)e * H * H, w2l + (size_t)e * H * H,
        eb2 + (size_t)e * H, eg2 + (size_t)e * H, ebt2 + (size_t)e * H,
        hh, hl, nullptr, nullptr, nullptr, 0, B);
    mfma_gemm<256, 128, 2><<<grid, 128, 0, stream>>>(
        hh, hl, w3h + (size_t)e * O * H, w3l + (size_t)e * O * H,
        eb3 + (size_t)e * O, eg3 + (size_t)e * O, ebt3 + (size_t)e * O,
        nullptr, nullptr, out, gwb, sgwb, e, B);
  }
}

// Round 4
// 1094.481 us; speedup vs baseline: 2.2844x; 1.4029x over previous
//
#include <hip/hip_runtime.h>
#include <math.h>

typedef __attribute__((ext_vector_type(8))) short short8;   // 8 bf16 = 4 VGPRs
typedef __attribute__((ext_vector_type(4))) float float4v;  // MFMA C/D

// ---------------- scalar conversion helpers --------------------------------
static __device__ __forceinline__ unsigned short f2bf(float f) {
  unsigned u = __float_as_uint(f);
  u += 0x7fffu + ((u >> 16) & 1u);
  return (unsigned short)(u >> 16);
}
static __device__ __forceinline__ float bf2f(unsigned short h) {
  return __uint_as_float(((unsigned)h) << 16);
}
static __device__ __forceinline__ unsigned short f2h(float f) {
  union { _Float16 h; unsigned short u; } c;
  c.h = (_Float16)f;
  return c.u;
}
static __device__ __forceinline__ float h2f(unsigned short u) {
  union { unsigned short u; _Float16 h; } c;
  c.u = u;
  return (float)c.h;
}

// ---------------------------------------------------------------------------
// split_wT: weights [nmat][K][N] fp32 -> transposed bf16 hi/lo [nmat][N][K].
// ---------------------------------------------------------------------------
__global__ __launch_bounds__(256)
void split_wT(const float* __restrict__ src, unsigned short* __restrict__ dh,
              unsigned short* __restrict__ dl, int K, int N) {
  __shared__ float t[32][33];
  const size_t mo = (size_t)blockIdx.z * K * N;
  src += mo; dh += mo; dl += mo;
  const int k0 = blockIdx.x * 32, n0 = blockIdx.y * 32;
  const int tid = threadIdx.x;
  const int r = tid >> 3, c4 = (tid & 7) * 4;

  const float4 v = *(const float4*)(src + (size_t)(k0 + r) * N + n0 + c4);
  t[r][c4 + 0] = v.x; t[r][c4 + 1] = v.y; t[r][c4 + 2] = v.z; t[r][c4 + 3] = v.w;
  __syncthreads();

  ushort4 hv, lv;
  float f;
  f = t[c4 + 0][r]; hv.x = f2bf(f); lv.x = f2bf(f - bf2f(hv.x));
  f = t[c4 + 1][r]; hv.y = f2bf(f); lv.y = f2bf(f - bf2f(hv.y));
  f = t[c4 + 2][r]; hv.z = f2bf(f); lv.z = f2bf(f - bf2f(hv.z));
  f = t[c4 + 3][r]; hv.w = f2bf(f); lv.w = f2bf(f - bf2f(hv.w));
  const size_t o = (size_t)(n0 + r) * K + k0 + c4;
  *(ushort4*)(dh + o) = hv;
  *(ushort4*)(dl + o) = lv;
}

// ---------------------------------------------------------------------------
// MFMA GEMM: C[M,N] = A[M,K] @ B^T[N,K], 16x16x32 bf16 split (AhBh+AhBl+AlBh).
// Block = 256 thr = 4 waves; tile = 64 rows x full N. Wave w owns cols
// [w*N/4, (w+1)*N/4): 4 m-subtiles x NT n-tiles each. LN is cross-wave via
// LDS partial (sum, sumsq). A is fp32 (split on the fly) or pre-split bf16.
// MODE 0: bias+LN+ReLU -> split bf16 (outh/outl). MODE 1: bias+ReLU -> fp32.
// MODE 2: bias+LN+ReLU -> fp16 (outh = bit buffer).
// Epilogue for MODE 0/2 repacks through LDS -> coalesced b128 stores.
// ---------------------------------------------------------------------------
template<int K, int N, int MODE, bool AF32>
__global__ __launch_bounds__(256, 3)
void mfma_gemm(const float* __restrict__ Af,
               const unsigned short* __restrict__ Ah,
               const unsigned short* __restrict__ Al,
               const unsigned short* __restrict__ Bh,
               const unsigned short* __restrict__ Bl,
               const float* __restrict__ bias, const float* __restrict__ gamma,
               const float* __restrict__ beta,
               unsigned short* __restrict__ outh,
               unsigned short* __restrict__ outl,
               float* __restrict__ outf) {
  constexpr int NW = N / 4;    // cols per wave
  constexpr int NT = NW / 16;  // n-tiles per wave (4 / 2 / 1)
  constexpr int NB = N / 64;   // B-staging chunks per thread per buffer
  __shared__ __align__(16) unsigned short lAh[64 * 40];
  __shared__ __align__(16) unsigned short lAl[64 * 40];
  __shared__ __align__(16) unsigned short lB[2][N * 40];
  __shared__ float sumP[64][4];
  __shared__ float sqP[64][4];

  const int tid = threadIdx.x;
  const int w = tid >> 6, lane = tid & 63, m = lane & 15, q = lane >> 4;
  const int m0 = blockIdx.x * 64;
  const int n0 = w * NW;
  const int arow = tid >> 2, ap = tid & 3;

  float4v acc[4][NT];
  #pragma unroll
  for (int s = 0; s < 4; ++s)
    #pragma unroll
    for (int t = 0; t < NT; ++t) acc[s][t] = (float4v){0.f, 0.f, 0.f, 0.f};

  for (int kt = 0; kt < K; kt += 32) {
    // ---- global loads into regs ----
    short8 ra, rla;
    if constexpr (AF32) {
      const float* src = Af + (size_t)(m0 + arow) * K + kt + ap * 8;
      const float4 f0 = *(const float4*)src;
      const float4 f1 = *(const float4*)(src + 4);
      const float fv[8] = {f0.x, f0.y, f0.z, f0.w, f1.x, f1.y, f1.z, f1.w};
      #pragma unroll
      for (int j = 0; j < 8; ++j) {
        const unsigned short hb = f2bf(fv[j]);
        ra[j]  = (short)hb;
        rla[j] = (short)f2bf(fv[j] - bf2f(hb));
      }
    } else {
      const size_t go = (size_t)(m0 + arow) * K + kt + ap * 8;
      ra  = *(const short8*)(Ah + go);
      rla = *(const short8*)(Al + go);
    }
    short8 rb[NB], rlb[NB];
    #pragma unroll
    for (int i = 0; i < NB; ++i) {
      const int c = tid + i * 256, n = c >> 2, p2 = c & 3;
      const size_t go = (size_t)n * K + kt + p2 * 8;
      rb[i]  = *(const short8*)(Bh + go);
      rlb[i] = *(const short8*)(Bl + go);
    }
    __syncthreads();
    *(short8*)(&lAh[arow * 40 + ap * 8]) = ra;
    *(short8*)(&lAl[arow * 40 + ap * 8]) = rla;
    #pragma unroll
    for (int i = 0; i < NB; ++i) {
      const int c = tid + i * 256, n = c >> 2, p2 = c & 3;
      *(short8*)(&lB[0][n * 40 + p2 * 8]) = rb[i];
      *(short8*)(&lB[1][n * 40 + p2 * 8]) = rlb[i];
    }
    __syncthreads();
    // ---- fragments + MFMA ----
    short8 ahf[4], alf[4];
    #pragma unroll
    for (int s = 0; s < 4; ++s) {
      const int off = (s * 16 + m) * 40 + q * 8;
      ahf[s] = *(const short8*)(&lAh[off]);
      alf[s] = *(const short8*)(&lAl[off]);
    }
    #pragma unroll
    for (int t = 0; t < NT; ++t) {
      const int boff = (n0 + t * 16 + m) * 40 + q * 8;
      const short8 bh = *(const short8*)(&lB[0][boff]);
      const short8 bl = *(const short8*)(&lB[1][boff]);
      #pragma unroll
      for (int s = 0; s < 4; ++s) {
        acc[s][t] = __builtin_amdgcn_mfma_f32_16x16x32_bf16(ahf[s], bh, acc[s][t], 0, 0, 0);
        acc[s][t] = __builtin_amdgcn_mfma_f32_16x16x32_bf16(ahf[s], bl, acc[s][t], 0, 0, 0);
        acc[s][t] = __builtin_amdgcn_mfma_f32_16x16x32_bf16(alf[s], bh, acc[s][t], 0, 0, 0);
      }
    }
  }

  // ---- epilogue ----
  float cb[NT], cg[NT], cbt[NT];
  #pragma unroll
  for (int t = 0; t < NT; ++t) {
    const int col = n0 + t * 16 + m;
    cb[t] = bias[col];
    if constexpr (MODE != 1) { cg[t] = gamma[col]; cbt[t] = beta[col]; }
  }

  if constexpr (MODE == 1) {  // bias + ReLU -> fp32 (elementwise, no LN)
    #pragma unroll
    for (int s = 0; s < 4; ++s)
      #pragma unroll
      for (int r = 0; r < 4; ++r) {
        const int row = s * 16 + q * 4 + r;
        #pragma unroll
        for (int t = 0; t < NT; ++t) {
          const float o = fmaxf(acc[s][t][r] + cb[t], 0.f);
          outf[(size_t)(m0 + row) * N + n0 + t * 16 + m] = o;
        }
      }
    return;
  } else {
    // ---- cross-wave LN: partial (sum, sumsq) per row per wave ----
    #pragma unroll
    for (int s = 0; s < 4; ++s)
      #pragma unroll
      for (int r = 0; r < 4; ++r) {
        float s1 = 0.f, s2 = 0.f;
        #pragma unroll
        for (int t = 0; t < NT; ++t) {
          const float v = acc[s][t][r] + cb[t];
          s1 += v; s2 += v * v;
        }
        #pragma unroll
        for (int off = 1; off < 16; off <<= 1) {
          s1 += __shfl_xor(s1, off, 16);
          s2 += __shfl_xor(s2, off, 16);
        }
        if (m == 0) {
          const int row = s * 16 + q * 4 + r;
          sumP[row][w] = s1;
          sqP[row][w] = s2;
        }
      }
    __syncthreads();

    float mean16[4][4], inv16[4][4];
    #pragma unroll
    for (int s = 0; s < 4; ++s)
      #pragma unroll
      for (int r = 0; r < 4; ++r) {
        const int row = s * 16 + q * 4 + r;
        const float S1 = sumP[row][0] + sumP[row][1] + sumP[row][2] + sumP[row][3];
        const float S2 = sqP[row][0] + sqP[row][1] + sqP[row][2] + sqP[row][3];
        const float mean = S1 * (1.f / N);
        const float var = S2 * (1.f / N) - mean * mean;
        mean16[s][r] = mean;
        inv16[s][r] = rsqrtf(var + 1e-5f);
      }

    // ---- repack through LDS -> coalesced b128 stores ----
    constexpr int RS = N + 8;               // ushort stride (16B-aligned rows)
    unsigned short* rp = &lB[0][0];
    constexpr int NPASS = (MODE == 0) ? 2 : 1;
    constexpr int CH = (64 * (N / 8)) / 256;  // store chunks per thread
    #pragma unroll
    for (int pass = 0; pass < NPASS; ++pass) {
      __syncthreads();
      #pragma unroll
      for (int s = 0; s < 4; ++s)
        #pragma unroll
        for (int r = 0; r < 4; ++r) {
          const int row = s * 16 + q * 4 + r;
          #pragma unroll
          for (int t = 0; t < NT; ++t) {
            const float v = acc[s][t][r] + cb[t];
            const float o =
                fmaxf((v - mean16[s][r]) * inv16[s][r] * cg[t] + cbt[t], 0.f);
            unsigned short val;
            if constexpr (MODE == 0) {
              const unsigned short hb = f2bf(o);
              val = pass ? f2bf(o - bf2f(hb)) : hb;
            } else {
              val = f2h(o);
            }
            rp[row * RS + n0 + t * 16 + m] = val;
          }
        }
      __syncthreads();
      unsigned short* dst = (MODE == 0) ? (pass ? outl : outh) : outh;
      #pragma unroll
      for (int i = 0; i < CH; ++i) {
        const int c = tid + i * 256;
        const int rowc = c / (N / 8), c8 = c % (N / 8);
        *(short8*)(dst + (size_t)(m0 + rowc) * N + c8 * 8) =
            *(const short8*)(&rp[rowc * RS + c8 * 8]);
      }
    }
  }
}

// ---------------------------------------------------------------------------
// Gating layer 2: softmax(gh @ w2 + b2) over NOUT outputs.
// ---------------------------------------------------------------------------
template<int NOUT>
__global__ __launch_bounds__(256)
void gate2(const float* __restrict__ gh, const float* __restrict__ w2,
           const float* __restrict__ b2, float* __restrict__ outw, int B) {
  const int b0 = blockIdx.x * 64;
  __shared__ float ghs[64][65];
  __shared__ float wls[64 * NOUT];
  __shared__ float bls[NOUT];
  const int tid = threadIdx.x;

  const float* src = gh + (size_t)b0 * 64;
  for (int f = tid; f < 64 * 16; f += 256) {
    const int r = f >> 4, c4 = f & 15;
    const float4 v = *(const float4*)(src + r * 64 + c4 * 4);
    ghs[r][c4 * 4 + 0] = v.x;
    ghs[r][c4 * 4 + 1] = v.y;
    ghs[r][c4 * 4 + 2] = v.z;
    ghs[r][c4 * 4 + 3] = v.w;
  }
  for (int f = tid; f < 64 * NOUT; f += 256) wls[f] = w2[f];
  if (tid < NOUT) bls[tid] = b2[tid];
  __syncthreads();

  if (tid < 64) {
    const int b = b0 + tid;
    float a[NOUT];
    #pragma unroll
    for (int n = 0; n < NOUT; ++n) a[n] = bls[n];
    for (int k = 0; k < 64; ++k) {
      const float g = ghs[tid][k];
      #pragma unroll
      for (int n = 0; n < NOUT; ++n) a[n] = fmaf(g, wls[k * NOUT + n], a[n]);
    }
    float mx = a[0];
    #pragma unroll
    for (int n = 1; n < NOUT; ++n) mx = fmaxf(mx, a[n]);
    float sum = 0.f;
    #pragma unroll
    for (int n = 0; n < NOUT; ++n) { a[n] = expf(a[n] - mx); sum += a[n]; }
    const float r = 1.f / sum;
    #pragma unroll
    for (int n = 0; n < NOUT; ++n) outw[(size_t)b * NOUT + n] = a[n] * r;
  }
}

// ---------------------------------------------------------------------------
// Final combine (single pass): out[s][b][:] = sum_e coef(s,e,b) * eo[e][b][:]
// Thread = (b, 8-col chunk). eo is fp16 bits.
// ---------------------------------------------------------------------------
__global__ __launch_bounds__(256)
void combine(const unsigned short* __restrict__ eo, const float* __restrict__ gw,
             const float* __restrict__ sgw, float* __restrict__ out, int B) {
  const int tid = threadIdx.x;
  const int gb = blockIdx.x * 16 + (tid >> 4);
  const int c0 = (tid & 15) * 8;

  float a[4][8];
  #pragma unroll
  for (int s = 0; s < 4; ++s)
    #pragma unroll
    for (int i = 0; i < 8; ++i) a[s][i] = 0.f;

  #pragma unroll
  for (int e = 0; e < 10; ++e) {
    const short8 vv = *(const short8*)(eo + ((size_t)e * B + gb) * 128 + c0);
    float f[8];
    #pragma unroll
    for (int i = 0; i < 8; ++i) f[i] = h2f((unsigned short)vv[i]);
    float c[4];
    c[3] = sgw[(size_t)gb * 10 + e];
    c[0] = c[1] = c[2] = 0.f;
    if (e < 4) {
      c[0] = gw[((size_t)0 * B + gb) * 6 + e];
      c[1] = gw[((size_t)1 * B + gb) * 6 + e];
      c[2] = gw[((size_t)2 * B + gb) * 6 + e];
    } else {
      const int tt = (e - 4) >> 1;
      c[tt] = gw[((size_t)tt * B + gb) * 6 + 4 + ((e - 4) & 1)];
    }
    #pragma unroll
    for (int s = 0; s < 4; ++s)
      #pragma unroll
      for (int i = 0; i < 8; ++i) a[s][i] = fmaf(c[s], f[i], a[s][i]);
  }

  #pragma unroll
  for (int s = 0; s < 4; ++s) {
    float* p = out + ((size_t)s * B + gb) * 128 + c0;
    const float4 v0 = {a[s][0], a[s][1], a[s][2], a[s][3]};
    const float4 v1 = {a[s][4], a[s][5], a[s][6], a[s][7]};
    *(float4*)p = v0;
    *(float4*)(p + 4) = v1;
  }
}

// ---------------------------------------------------------------------------
extern "C" void kernel_launch(void* const* d_in, const int* in_sizes, int n_in,
                              void* d_out, int out_size, void* d_ws, size_t ws_size,
                              hipStream_t stream) {
  const float* x     = (const float*)d_in[0];
  const float* ew1   = (const float*)d_in[1];
  const float* eb1   = (const float*)d_in[2];
  const float* eg1   = (const float*)d_in[3];
  const float* ebt1  = (const float*)d_in[4];
  const float* ew2   = (const float*)d_in[5];
  const float* eb2   = (const float*)d_in[6];
  const float* eg2   = (const float*)d_in[7];
  const float* ebt2  = (const float*)d_in[8];
  const float* ew3   = (const float*)d_in[9];
  const float* eb3   = (const float*)d_in[10];
  const float* eg3   = (const float*)d_in[11];
  const float* ebt3  = (const float*)d_in[12];
  const float* tg_w1 = (const float*)d_in[13];
  const float* tg_b1 = (const float*)d_in[14];
  const float* tg_w2 = (const float*)d_in[15];
  const float* tg_b2 = (const float*)d_in[16];
  const float* sg_w1 = (const float*)d_in[17];
  const float* sg_b1 = (const float*)d_in[18];
  const float* sg_w2 = (const float*)d_in[19];
  const float* sg_b2 = (const float*)d_in[20];
  float* out = (float*)d_out;

  const int B = 32768, D = 512, H = 256, O = 128, G = 64, E = 10;

  // ---- workspace layout (bytes), total ~130.8 MB ----
  char* p = (char*)d_ws;
  unsigned short* w1h  = (unsigned short*)p; p += (size_t)E * H * D * 2;
  unsigned short* w1l  = (unsigned short*)p; p += (size_t)E * H * D * 2;
  unsigned short* w2h  = (unsigned short*)p; p += (size_t)E * H * H * 2;
  unsigned short* w2l  = (unsigned short*)p; p += (size_t)E * H * H * 2;
  unsigned short* w3h  = (unsigned short*)p; p += (size_t)E * O * H * 2;
  unsigned short* w3l  = (unsigned short*)p; p += (size_t)E * O * H * 2;
  unsigned short* tw1h = (unsigned short*)p; p += (size_t)3 * G * D * 2;
  unsigned short* tw1l = (unsigned short*)p; p += (size_t)3 * G * D * 2;
  unsigned short* sw1h = (unsigned short*)p; p += (size_t)G * D * 2;
  unsigned short* sw1l = (unsigned short*)p; p += (size_t)G * D * 2;
  unsigned short* hh   = (unsigned short*)p; p += (size_t)B * H * 2;
  unsigned short* hl   = (unsigned short*)p; p += (size_t)B * H * 2;
  float* gwb  = (float*)p; p += (size_t)3 * B * 6 * 4;
  float* sgwb = (float*)p; p += (size_t)B * 10 * 4;
  unsigned short* eo = (unsigned short*)p;   // E*B*128 fp16 (83.9 MB)
  float* gh = (float*)eo;                     // overlay: gating phase only

  const int grid = B / 64;

  // ---- 1. weight conversions ----
  split_wT<<<dim3(D / 32, H / 32, E), 256, 0, stream>>>(ew1, w1h, w1l, D, H);
  split_wT<<<dim3(H / 32, H / 32, E), 256, 0, stream>>>(ew2, w2h, w2l, H, H);
  split_wT<<<dim3(H / 32, O / 32, E), 256, 0, stream>>>(ew3, w3h, w3l, H, O);
  split_wT<<<dim3(D / 32, G / 32, 3), 256, 0, stream>>>(tg_w1, tw1h, tw1l, D, G);
  split_wT<<<dim3(D / 32, G / 32, 1), 256, 0, stream>>>(sg_w1, sw1h, sw1l, D, G);

  // ---- 2. gating (x fp32 split on the fly) ----
  for (int t = 0; t < 4; ++t) {
    const unsigned short* Wh = (t < 3) ? tw1h + (size_t)t * G * D : sw1h;
    const unsigned short* Wl = (t < 3) ? tw1l + (size_t)t * G * D : sw1l;
    const float* b1 = (t < 3) ? tg_b1 + (size_t)t * G : sg_b1;
    mfma_gemm<512, 64, 1, true><<<grid, 256, 0, stream>>>(
        x, nullptr, nullptr, Wh, Wl, b1, nullptr, nullptr,
        nullptr, nullptr, gh);
    if (t < 3)
      gate2<6><<<B / 64, 256, 0, stream>>>(gh, tg_w2 + (size_t)t * G * 6,
                                           tg_b2 + (size_t)t * 6,
                                           gwb + (size_t)t * B * 6, B);
    else
      gate2<10><<<B / 64, 256, 0, stream>>>(gh, sg_w2, sg_b2, sgwb, B);
  }

  // ---- 3. expert towers (L2 in-place on h; L3 -> fp16 eo) ----
  for (int e = 0; e < E; ++e) {
    mfma_gemm<512, 256, 0, true><<<grid, 256, 0, stream>>>(
        x, nullptr, nullptr, w1h + (size_t)e * H * D, w1l + (size_t)e * H * D,
        eb1 + (size_t)e * H, eg1 + (size_t)e * H, ebt1 + (size_t)e * H,
        hh, hl, nullptr);
    mfma_gemm<256, 256, 0, false><<<grid, 256, 0, stream>>>(
        nullptr, hh, hl, w2h + (size_t)e * H * H, w2l + (size_t)e * H * H,
        eb2 + (size_t)e * H, eg2 + (size_t)e * H, ebt2 + (size_t)e * H,
        hh, hl, nullptr);
    mfma_gemm<256, 128, 2, false><<<grid, 256, 0, stream>>>(
        nullptr, hh, hl, w3h + (size_t)e * O * H, w3l + (size_t)e * O * H,
        eb3 + (size_t)e * O, eg3 + (size_t)e * O, ebt3 + (size_t)e * O,
        eo + (size_t)e * B * O, nullptr, nullptr);
  }

  // ---- 4. single-pass combine ----
  combine<<<B / 16, 256, 0, stream>>>(eo, gwb, sgwb, out, B);
}

// Round 5
// 821.113 us; speedup vs baseline: 3.0449x; 1.3329x over previous
//
#include <hip/hip_runtime.h>
#include <math.h>

typedef __attribute__((ext_vector_type(8))) _Float16 half8;  // 8 fp16 = 4 VGPRs
typedef __attribute__((ext_vector_type(8))) short short8;
typedef __attribute__((ext_vector_type(4))) float float4v;

// ---------------- fp16 helpers ---------------------------------------------
static __device__ __forceinline__ unsigned short f2h(float f) {
  union { _Float16 h; unsigned short u; } c;
  c.h = (_Float16)f;
  return c.u;
}
static __device__ __forceinline__ float h2f(unsigned short u) {
  union { unsigned short u; _Float16 h; } c;
  c.u = u;
  return (float)c.h;
}

// ---------------------------------------------------------------------------
// split_wT: weights [nmat][K][N] fp32 -> transposed fp16 hi/lo [nmat][N][K].
// ---------------------------------------------------------------------------
__global__ __launch_bounds__(256)
void split_wT(const float* __restrict__ src, unsigned short* __restrict__ dh,
              unsigned short* __restrict__ dl, int K, int N) {
  __shared__ float t[32][33];
  const size_t mo = (size_t)blockIdx.z * K * N;
  src += mo; dh += mo; dl += mo;
  const int k0 = blockIdx.x * 32, n0 = blockIdx.y * 32;
  const int tid = threadIdx.x;
  const int r = tid >> 3, c4 = (tid & 7) * 4;

  const float4 v = *(const float4*)(src + (size_t)(k0 + r) * N + n0 + c4);
  t[r][c4 + 0] = v.x; t[r][c4 + 1] = v.y; t[r][c4 + 2] = v.z; t[r][c4 + 3] = v.w;
  __syncthreads();

  ushort4 hv, lv;
  #pragma unroll
  for (int j = 0; j < 4; ++j) {
    const float f = t[c4 + j][r];
    const unsigned short hb = f2h(f);
    ((unsigned short*)&hv)[j] = hb;
    ((unsigned short*)&lv)[j] = f2h(f - h2f(hb));
  }
  const size_t o = (size_t)(n0 + r) * K + k0 + c4;
  *(ushort4*)(dh + o) = hv;
  *(ushort4*)(dl + o) = lv;
}

// ---------------------------------------------------------------------------
// LN (+bias) + ReLU epilogue over N cols (4 waves, col-split), then store
// fp16 bits to dst[row * dstride + col]. Ends with a barrier.
// ---------------------------------------------------------------------------
template<int N, int NT>
__device__ __forceinline__ void ln_store_f16(
    float4v (*acc)[4], int w, int m, int q,
    const float* __restrict__ bias, const float* __restrict__ gamma,
    const float* __restrict__ beta,
    unsigned short* __restrict__ dst, int dstride,
    float (*sumP)[4], float (*sqP)[4]) {
  constexpr int NW = N / 4;
  float cb[NT], cg[NT], cbt[NT];
  #pragma unroll
  for (int t = 0; t < NT; ++t) {
    const int col = w * NW + t * 16 + m;
    cb[t] = bias[col]; cg[t] = gamma[col]; cbt[t] = beta[col];
  }
  #pragma unroll
  for (int s = 0; s < 4; ++s)
    #pragma unroll
    for (int r = 0; r < 4; ++r) {
      float s1 = 0.f, s2 = 0.f;
      #pragma unroll
      for (int t = 0; t < NT; ++t) {
        const float v = acc[s][t][r] + cb[t];
        s1 += v; s2 += v * v;
      }
      #pragma unroll
      for (int off = 1; off < 16; off <<= 1) {
        s1 += __shfl_xor(s1, off, 16);
        s2 += __shfl_xor(s2, off, 16);
      }
      if (m == 0) {
        sumP[s * 16 + q * 4 + r][w] = s1;
        sqP[s * 16 + q * 4 + r][w] = s2;
      }
    }
  __syncthreads();
  #pragma unroll
  for (int s = 0; s < 4; ++s)
    #pragma unroll
    for (int r = 0; r < 4; ++r) {
      const int row = s * 16 + q * 4 + r;
      const float S1 = sumP[row][0] + sumP[row][1] + sumP[row][2] + sumP[row][3];
      const float S2 = sqP[row][0] + sqP[row][1] + sqP[row][2] + sqP[row][3];
      const float mean = S1 * (1.f / N);
      const float var = S2 * (1.f / N) - mean * mean;
      const float inv = rsqrtf(var + 1e-5f);
      #pragma unroll
      for (int t = 0; t < NT; ++t) {
        const float o =
            fmaxf((acc[s][t][r] + cb[t] - mean) * inv * cg[t] + cbt[t], 0.f);
        dst[row * dstride + w * NW + t * 16 + m] = f2h(o);
      }
    }
  __syncthreads();
}

// ---------------------------------------------------------------------------
// Fused expert tower: one block = 64 batch rows x one expert (blockIdx.y).
// Phase1: x[64,512] @ W1^T -> LN/ReLU -> h (fp16, LDS only)
// Phase2: h @ W2^T -> LN/ReLU -> h      Phase3: h @ W3^T -> LN/ReLU -> eo fp16
// fp16 split weights (hi/lo); x split on the fly. Phase1 = 3-term MFMA,
// phases 2/3 = 2-term (A is single fp16, B split).
// LDS pool: [0,16896): phase1 A-staging (2x2560) then hbuf 64x264;
//           [16896,37376): B staging hi/lo (256x40 each).
// ---------------------------------------------------------------------------
__global__ __launch_bounds__(256, 2)
void expert_tower(const float* __restrict__ x,
                  const unsigned short* __restrict__ w1h,
                  const unsigned short* __restrict__ w1l,
                  const float* __restrict__ eb1, const float* __restrict__ eg1,
                  const float* __restrict__ ebt1,
                  const unsigned short* __restrict__ w2h,
                  const unsigned short* __restrict__ w2l,
                  const float* __restrict__ eb2, const float* __restrict__ eg2,
                  const float* __restrict__ ebt2,
                  const unsigned short* __restrict__ w3h,
                  const unsigned short* __restrict__ w3l,
                  const float* __restrict__ eb3, const float* __restrict__ eg3,
                  const float* __restrict__ ebt3,
                  unsigned short* __restrict__ eo, int B) {
  __shared__ __align__(16) unsigned short pool[37376];
  __shared__ float sumP[64][4];
  __shared__ float sqP[64][4];

  const int tid = threadIdx.x;
  const int w = tid >> 6, lane = tid & 63, m = lane & 15, q = lane >> 4;
  const int m0 = blockIdx.x * 64;
  const int e = blockIdx.y;
  const int arow = tid >> 2, ap = tid & 3;

  unsigned short* lAh = pool;            // 64*40 (phase 1 k-loop only)
  unsigned short* lAl = pool + 2560;
  unsigned short* hbuf = pool;           // 64*264 (from phase-1 epilogue on)
  unsigned short* lBh = pool + 16896;    // 256*40
  unsigned short* lBl = pool + 27136;    // 256*40

  w1h += (size_t)e * 256 * 512; w1l += (size_t)e * 256 * 512;
  w2h += (size_t)e * 256 * 256; w2l += (size_t)e * 256 * 256;
  w3h += (size_t)e * 128 * 256; w3l += (size_t)e * 128 * 256;
  eb1 += (size_t)e * 256; eg1 += (size_t)e * 256; ebt1 += (size_t)e * 256;
  eb2 += (size_t)e * 256; eg2 += (size_t)e * 256; ebt2 += (size_t)e * 256;
  eb3 += (size_t)e * 128; eg3 += (size_t)e * 128; ebt3 += (size_t)e * 128;

  float4v acc[4][4];

  // ================= phase 1: K=512, N=256, 3-term ==========================
  #pragma unroll
  for (int s = 0; s < 4; ++s)
    #pragma unroll
    for (int t = 0; t < 4; ++t) acc[s][t] = (float4v){0.f, 0.f, 0.f, 0.f};

  for (int kt = 0; kt < 512; kt += 32) {
    // x fp32 -> fp16 hi/lo split on the fly
    const float* src = x + (size_t)(m0 + arow) * 512 + kt + ap * 8;
    const float4 f0 = *(const float4*)src;
    const float4 f1 = *(const float4*)(src + 4);
    const float fv[8] = {f0.x, f0.y, f0.z, f0.w, f1.x, f1.y, f1.z, f1.w};
    half8 ra, rla;
    #pragma unroll
    for (int j = 0; j < 8; ++j) {
      const _Float16 hb = (_Float16)fv[j];
      ra[j] = hb;
      rla[j] = (_Float16)(fv[j] - (float)hb);
    }
    short8 rb[4], rlb[4];
    #pragma unroll
    for (int i = 0; i < 4; ++i) {
      const int c = tid + i * 256, n = c >> 2, p2 = c & 3;
      rb[i]  = *(const short8*)(w1h + (size_t)n * 512 + kt + p2 * 8);
      rlb[i] = *(const short8*)(w1l + (size_t)n * 512 + kt + p2 * 8);
    }
    __syncthreads();
    *(half8*)(lAh + arow * 40 + ap * 8) = ra;
    *(half8*)(lAl + arow * 40 + ap * 8) = rla;
    #pragma unroll
    for (int i = 0; i < 4; ++i) {
      const int c = tid + i * 256, n = c >> 2, p2 = c & 3;
      *(short8*)(lBh + n * 40 + p2 * 8) = rb[i];
      *(short8*)(lBl + n * 40 + p2 * 8) = rlb[i];
    }
    __syncthreads();
    half8 ah[4], al[4];
    #pragma unroll
    for (int s = 0; s < 4; ++s) {
      const int off = (s * 16 + m) * 40 + q * 8;
      ah[s] = *(const half8*)(lAh + off);
      al[s] = *(const half8*)(lAl + off);
    }
    #pragma unroll
    for (int t = 0; t < 4; ++t) {
      const int boff = (w * 64 + t * 16 + m) * 40 + q * 8;
      const half8 bh = *(const half8*)(lBh + boff);
      const half8 bl = *(const half8*)(lBl + boff);
      #pragma unroll
      for (int s = 0; s < 4; ++s) {
        acc[s][t] = __builtin_amdgcn_mfma_f32_16x16x32_f16(ah[s], bh, acc[s][t], 0, 0, 0);
        acc[s][t] = __builtin_amdgcn_mfma_f32_16x16x32_f16(al[s], bh, acc[s][t], 0, 0, 0);
        acc[s][t] = __builtin_amdgcn_mfma_f32_16x16x32_f16(ah[s], bl, acc[s][t], 0, 0, 0);
      }
    }
  }
  ln_store_f16<256, 4>(acc, w, m, q, eb1, eg1, ebt1, hbuf, 264, sumP, sqP);

  // ================= phase 2: K=256, N=256, 2-term ==========================
  #pragma unroll
  for (int s = 0; s < 4; ++s)
    #pragma unroll
    for (int t = 0; t < 4; ++t) acc[s][t] = (float4v){0.f, 0.f, 0.f, 0.f};

  for (int kt = 0; kt < 256; kt += 32) {
    short8 rb[4], rlb[4];
    #pragma unroll
    for (int i = 0; i < 4; ++i) {
      const int c = tid + i * 256, n = c >> 2, p2 = c & 3;
      rb[i]  = *(const short8*)(w2h + (size_t)n * 256 + kt + p2 * 8);
      rlb[i] = *(const short8*)(w2l + (size_t)n * 256 + kt + p2 * 8);
    }
    __syncthreads();
    #pragma unroll
    for (int i = 0; i < 4; ++i) {
      const int c = tid + i * 256, n = c >> 2, p2 = c & 3;
      *(short8*)(lBh + n * 40 + p2 * 8) = rb[i];
      *(short8*)(lBl + n * 40 + p2 * 8) = rlb[i];
    }
    __syncthreads();
    half8 ah[4];
    #pragma unroll
    for (int s = 0; s < 4; ++s)
      ah[s] = *(const half8*)(hbuf + (s * 16 + m) * 264 + kt + q * 8);
    #pragma unroll
    for (int t = 0; t < 4; ++t) {
      const int boff = (w * 64 + t * 16 + m) * 40 + q * 8;
      const half8 bh = *(const half8*)(lBh + boff);
      const half8 bl = *(const half8*)(lBl + boff);
      #pragma unroll
      for (int s = 0; s < 4; ++s) {
        acc[s][t] = __builtin_amdgcn_mfma_f32_16x16x32_f16(ah[s], bh, acc[s][t], 0, 0, 0);
        acc[s][t] = __builtin_amdgcn_mfma_f32_16x16x32_f16(ah[s], bl, acc[s][t], 0, 0, 0);
      }
    }
  }
  ln_store_f16<256, 4>(acc, w, m, q, eb2, eg2, ebt2, hbuf, 264, sumP, sqP);

  // ================= phase 3: K=256, N=128, 2-term ==========================
  #pragma unroll
  for (int s = 0; s < 4; ++s)
    #pragma unroll
    for (int t = 0; t < 2; ++t) acc[s][t] = (float4v){0.f, 0.f, 0.f, 0.f};

  for (int kt = 0; kt < 256; kt += 32) {
    short8 rb[2], rlb[2];
    #pragma unroll
    for (int i = 0; i < 2; ++i) {
      const int c = tid + i * 256, n = c >> 2, p2 = c & 3;
      rb[i]  = *(const short8*)(w3h + (size_t)n * 256 + kt + p2 * 8);
      rlb[i] = *(const short8*)(w3l + (size_t)n * 256 + kt + p2 * 8);
    }
    __syncthreads();
    #pragma unroll
    for (int i = 0; i < 2; ++i) {
      const int c = tid + i * 256, n = c >> 2, p2 = c & 3;
      *(short8*)(lBh + n * 40 + p2 * 8) = rb[i];
      *(short8*)(lBl + n * 40 + p2 * 8) = rlb[i];
    }
    __syncthreads();
    half8 ah[4];
    #pragma unroll
    for (int s = 0; s < 4; ++s)
      ah[s] = *(const half8*)(hbuf + (s * 16 + m) * 264 + kt + q * 8);
    #pragma unroll
    for (int t = 0; t < 2; ++t) {
      const int boff = (w * 32 + t * 16 + m) * 40 + q * 8;
      const half8 bh = *(const half8*)(lBh + boff);
      const half8 bl = *(const half8*)(lBl + boff);
      #pragma unroll
      for (int s = 0; s < 4; ++s) {
        acc[s][t] = __builtin_amdgcn_mfma_f32_16x16x32_f16(ah[s], bh, acc[s][t], 0, 0, 0);
        acc[s][t] = __builtin_amdgcn_mfma_f32_16x16x32_f16(ah[s], bl, acc[s][t], 0, 0, 0);
      }
    }
  }
  // epilogue 3 -> repack buffer (stride 136) -> coalesced fp16 stores to eo
  unsigned short* rp = pool;  // 64*136, overlays hbuf (reads all done)
  ln_store_f16<128, 2>(acc, w, m, q, eb3, eg3, ebt3, rp, 136, sumP, sqP);
  #pragma unroll
  for (int i = 0; i < 4; ++i) {
    const int c = tid + i * 256;
    const int rowc = c >> 4, c8 = c & 15;
    *(short8*)(eo + ((size_t)e * B + m0 + rowc) * 128 + c8 * 8) =
        *(const short8*)(rp + rowc * 136 + c8 * 8);
  }
}

// ---------------------------------------------------------------------------
// Gating hidden GEMM: gh[slice][b][64] = relu(x @ W^T + b). slice=blockIdx.y
// (0..2 task, 3 shared). fp16 split 3-term; x split on the fly.
// ---------------------------------------------------------------------------
__global__ __launch_bounds__(256, 2)
void gate_gemm(const float* __restrict__ x, const unsigned short* __restrict__ twh,
               const unsigned short* __restrict__ twl,
               const float* __restrict__ tg_b1, const float* __restrict__ sg_b1,
               float* __restrict__ gh, int B) {
  __shared__ __align__(16) unsigned short lAh[2560], lAl[2560];
  __shared__ __align__(16) unsigned short lBh[2560], lBl[2560];
  const int tid = threadIdx.x;
  const int w = tid >> 6, lane = tid & 63, m = lane & 15, q = lane >> 4;
  const int m0 = blockIdx.x * 64;
  const int slice = blockIdx.y;
  const int arow = tid >> 2, ap = tid & 3;
  twh += (size_t)slice * 64 * 512;
  twl += (size_t)slice * 64 * 512;
  const float* bias = (slice < 3) ? tg_b1 + (size_t)slice * 64 : sg_b1;

  float4v acc[4];
  #pragma unroll
  for (int s = 0; s < 4; ++s) acc[s] = (float4v){0.f, 0.f, 0.f, 0.f};

  for (int kt = 0; kt < 512; kt += 32) {
    const float* src = x + (size_t)(m0 + arow) * 512 + kt + ap * 8;
    const float4 f0 = *(const float4*)src;
    const float4 f1 = *(const float4*)(src + 4);
    const float fv[8] = {f0.x, f0.y, f0.z, f0.w, f1.x, f1.y, f1.z, f1.w};
    half8 ra, rla;
    #pragma unroll
    for (int j = 0; j < 8; ++j) {
      const _Float16 hb = (_Float16)fv[j];
      ra[j] = hb;
      rla[j] = (_Float16)(fv[j] - (float)hb);
    }
    const int n = tid >> 2, p2 = tid & 3;
    const short8 rb  = *(const short8*)(twh + (size_t)n * 512 + kt + p2 * 8);
    const short8 rlb = *(const short8*)(twl + (size_t)n * 512 + kt + p2 * 8);
    __syncthreads();
    *(half8*)(lAh + arow * 40 + ap * 8) = ra;
    *(half8*)(lAl + arow * 40 + ap * 8) = rla;
    *(short8*)(lBh + n * 40 + p2 * 8) = rb;
    *(short8*)(lBl + n * 40 + p2 * 8) = rlb;
    __syncthreads();
    const int boff = (w * 16 + m) * 40 + q * 8;
    const half8 bh = *(const half8*)(lBh + boff);
    const half8 bl = *(const half8*)(lBl + boff);
    #pragma unroll
    for (int s = 0; s < 4; ++s) {
      const int aoff = (s * 16 + m) * 40 + q * 8;
      const half8 ah = *(const half8*)(lAh + aoff);
      const half8 al = *(const half8*)(lAl + aoff);
      acc[s] = __builtin_amdgcn_mfma_f32_16x16x32_f16(ah, bh, acc[s], 0, 0, 0);
      acc[s] = __builtin_amdgcn_mfma_f32_16x16x32_f16(al, bh, acc[s], 0, 0, 0);
      acc[s] = __builtin_amdgcn_mfma_f32_16x16x32_f16(ah, bl, acc[s], 0, 0, 0);
    }
  }
  const float cb = bias[w * 16 + m];
  #pragma unroll
  for (int s = 0; s < 4; ++s)
    #pragma unroll
    for (int r = 0; r < 4; ++r) {
      const int row = m0 + s * 16 + q * 4 + r;
      gh[((size_t)slice * B + row) * 64 + w * 16 + m] =
          fmaxf(acc[s][r] + cb, 0.f);
    }
}

// ---------------------------------------------------------------------------
// Gating layer 2: softmax(gh @ w2 + b2) over NOUT outputs.
// ---------------------------------------------------------------------------
template<int NOUT>
__global__ __launch_bounds__(256)
void gate2(const float* __restrict__ gh, const float* __restrict__ w2,
           const float* __restrict__ b2, float* __restrict__ outw, int B) {
  const int b0 = blockIdx.x * 64;
  __shared__ float ghs[64][65];
  __shared__ float wls[64 * NOUT];
  __shared__ float bls[NOUT];
  const int tid = threadIdx.x;

  const float* src = gh + (size_t)b0 * 64;
  for (int f = tid; f < 64 * 16; f += 256) {
    const int r = f >> 4, c4 = f & 15;
    const float4 v = *(const float4*)(src + r * 64 + c4 * 4);
    ghs[r][c4 * 4 + 0] = v.x;
    ghs[r][c4 * 4 + 1] = v.y;
    ghs[r][c4 * 4 + 2] = v.z;
    ghs[r][c4 * 4 + 3] = v.w;
  }
  for (int f = tid; f < 64 * NOUT; f += 256) wls[f] = w2[f];
  if (tid < NOUT) bls[tid] = b2[tid];
  __syncthreads();

  if (tid < 64) {
    const int b = b0 + tid;
    float a[NOUT];
    #pragma unroll
    for (int n = 0; n < NOUT; ++n) a[n] = bls[n];
    for (int k = 0; k < 64; ++k) {
      const float g = ghs[tid][k];
      #pragma unroll
      for (int n = 0; n < NOUT; ++n) a[n] = fmaf(g, wls[k * NOUT + n], a[n]);
    }
    float mx = a[0];
    #pragma unroll
    for (int n = 1; n < NOUT; ++n) mx = fmaxf(mx, a[n]);
    float sum = 0.f;
    #pragma unroll
    for (int n = 0; n < NOUT; ++n) { a[n] = expf(a[n] - mx); sum += a[n]; }
    const float r = 1.f / sum;
    #pragma unroll
    for (int n = 0; n < NOUT; ++n) outw[(size_t)b * NOUT + n] = a[n] * r;
  }
}

// ---------------------------------------------------------------------------
// Final combine: out[s][b][:] = sum_e coef(s,e,b) * eo[e][b][:]  (eo fp16)
// ---------------------------------------------------------------------------
__global__ __launch_bounds__(256)
void combine(const unsigned short* __restrict__ eo, const float* __restrict__ gw,
             const float* __restrict__ sgw, float* __restrict__ out, int B) {
  const int tid = threadIdx.x;
  const int gb = blockIdx.x * 16 + (tid >> 4);
  const int c0 = (tid & 15) * 8;

  float a[4][8];
  #pragma unroll
  for (int s = 0; s < 4; ++s)
    #pragma unroll
    for (int i = 0; i < 8; ++i) a[s][i] = 0.f;

  #pragma unroll
  for (int e = 0; e < 10; ++e) {
    const half8 vv = *(const half8*)(eo + ((size_t)e * B + gb) * 128 + c0);
    float f[8];
    #pragma unroll
    for (int i = 0; i < 8; ++i) f[i] = (float)vv[i];
    float c[4];
    c[3] = sgw[(size_t)gb * 10 + e];
    c[0] = c[1] = c[2] = 0.f;
    if (e < 4) {
      c[0] = gw[((size_t)0 * B + gb) * 6 + e];
      c[1] = gw[((size_t)1 * B + gb) * 6 + e];
      c[2] = gw[((size_t)2 * B + gb) * 6 + e];
    } else {
      const int tt = (e - 4) >> 1;
      c[tt] = gw[((size_t)tt * B + gb) * 6 + 4 + ((e - 4) & 1)];
    }
    #pragma unroll
    for (int s = 0; s < 4; ++s)
      #pragma unroll
      for (int i = 0; i < 8; ++i) a[s][i] = fmaf(c[s], f[i], a[s][i]);
  }

  #pragma unroll
  for (int s = 0; s < 4; ++s) {
    float* p = out + ((size_t)s * B + gb) * 128 + c0;
    const float4 v0 = {a[s][0], a[s][1], a[s][2], a[s][3]};
    const float4 v1 = {a[s][4], a[s][5], a[s][6], a[s][7]};
    *(float4*)p = v0;
    *(float4*)(p + 4) = v1;
  }
}

// ---------------------------------------------------------------------------
extern "C" void kernel_launch(void* const* d_in, const int* in_sizes, int n_in,
                              void* d_out, int out_size, void* d_ws, size_t ws_size,
                              hipStream_t stream) {
  const float* x     = (const float*)d_in[0];
  const float* ew1   = (const float*)d_in[1];
  const float* eb1   = (const float*)d_in[2];
  const float* eg1   = (const float*)d_in[3];
  const float* ebt1  = (const float*)d_in[4];
  const float* ew2   = (const float*)d_in[5];
  const float* eb2   = (const float*)d_in[6];
  const float* eg2   = (const float*)d_in[7];
  const float* ebt2  = (const float*)d_in[8];
  const float* ew3   = (const float*)d_in[9];
  const float* eb3   = (const float*)d_in[10];
  const float* eg3   = (const float*)d_in[11];
  const float* ebt3  = (const float*)d_in[12];
  const float* tg_w1 = (const float*)d_in[13];
  const float* tg_b1 = (const float*)d_in[14];
  const float* tg_w2 = (const float*)d_in[15];
  const float* tg_b2 = (const float*)d_in[16];
  const float* sg_w1 = (const float*)d_in[17];
  const float* sg_b1 = (const float*)d_in[18];
  const float* sg_w2 = (const float*)d_in[19];
  const float* sg_b2 = (const float*)d_in[20];
  float* out = (float*)d_out;

  const int B = 32768, D = 512, H = 256, O = 128, G = 64, E = 10;

  // ---- workspace (bytes), total ~97 MB ----
  char* p = (char*)d_ws;
  unsigned short* w1h  = (unsigned short*)p; p += (size_t)E * H * D * 2;
  unsigned short* w1l  = (unsigned short*)p; p += (size_t)E * H * D * 2;
  unsigned short* w2h  = (unsigned short*)p; p += (size_t)E * H * H * 2;
  unsigned short* w2l  = (unsigned short*)p; p += (size_t)E * H * H * 2;
  unsigned short* w3h  = (unsigned short*)p; p += (size_t)E * O * H * 2;
  unsigned short* w3l  = (unsigned short*)p; p += (size_t)E * O * H * 2;
  unsigned short* tw1h = (unsigned short*)p; p += (size_t)4 * G * D * 2;
  unsigned short* tw1l = (unsigned short*)p; p += (size_t)4 * G * D * 2;
  float* gwb  = (float*)p; p += (size_t)3 * B * 6 * 4;
  float* sgwb = (float*)p; p += (size_t)B * 10 * 4;
  unsigned short* eo = (unsigned short*)p;   // E*B*O fp16 = 83.9 MB
  float* gh = (float*)eo;                    // overlay: gating phase only

  // ---- 1. weight conversions (fp16 split, transposed) ----
  split_wT<<<dim3(D / 32, H / 32, E), 256, 0, stream>>>(ew1, w1h, w1l, D, H);
  split_wT<<<dim3(H / 32, H / 32, E), 256, 0, stream>>>(ew2, w2h, w2l, H, H);
  split_wT<<<dim3(H / 32, O / 32, E), 256, 0, stream>>>(ew3, w3h, w3l, H, O);
  split_wT<<<dim3(D / 32, G / 32, 3), 256, 0, stream>>>(tg_w1, tw1h, tw1l, D, G);
  split_wT<<<dim3(D / 32, G / 32, 1), 256, 0, stream>>>(
      sg_w1, tw1h + (size_t)3 * G * D, tw1l + (size_t)3 * G * D, D, G);

  // ---- 2. gating ----
  gate_gemm<<<dim3(B / 64, 4), 256, 0, stream>>>(x, tw1h, tw1l, tg_b1, sg_b1,
                                                 gh, B);
  for (int t = 0; t < 3; ++t)
    gate2<6><<<B / 64, 256, 0, stream>>>(gh + (size_t)t * B * G,
                                         tg_w2 + (size_t)t * G * 6,
                                         tg_b2 + (size_t)t * 6,
                                         gwb + (size_t)t * B * 6, B);
  gate2<10><<<B / 64, 256, 0, stream>>>(gh + (size_t)3 * B * G, sg_w2, sg_b2,
                                        sgwb, B);

  // ---- 3. fused expert towers: one launch, all experts ----
  expert_tower<<<dim3(B / 64, E), 256, 0, stream>>>(
      x, w1h, w1l, eb1, eg1, ebt1, w2h, w2l, eb2, eg2, ebt2,
      w3h, w3l, eb3, eg3, ebt3, eo, B);

  // ---- 4. combine ----
  combine<<<B / 16, 256, 0, stream>>>(eo, gwb, sgwb, out, B);
}